// Round 1
// baseline (4168.736 us; speedup 1.0000x reference)
//
#include <hip/hip_runtime.h>
#include <math.h>

// Problem constants (match reference file)
#define F_IN   512
#define F_HID  256
#define N_CLS  41

// ---------------- degree / normalization ----------------

__global__ void init_deg(float* deg, int n) {
    int i = blockIdx.x * blockDim.x + threadIdx.x;
    if (i < n) deg[i] = 1.0f;  // self loop
}

__global__ void count_deg(const int* __restrict__ edst, float* deg, int E) {
    int e = blockIdx.x * blockDim.x + threadIdx.x;
    if (e < E) atomicAdd(&deg[edst[e]], 1.0f);
}

__global__ void rsqrt_deg(float* deg, int n) {
    int i = blockIdx.x * blockDim.x + threadIdx.x;
    if (i < n) deg[i] = rsqrtf(deg[i]);  // in place: deg -> dinv
}

// ---------------- SGEMM1: h1 = x @ W1  (M x 512) @ (512 x 256) ----------------
// 64x64 tile, BK=16, 256 threads, 4x4 per thread.

__global__ __launch_bounds__(256) void sgemm1(const float* __restrict__ A,
                                              const float* __restrict__ B,
                                              float* __restrict__ C, int M) {
    const int K = F_IN, N = F_HID;
    __shared__ float As[16][65];  // [k][m], +1 pad
    __shared__ float Bs[16][64];  // [k][n]
    int tid = threadIdx.x;
    int tx = tid & 15, ty = tid >> 4;
    int m0 = blockIdx.y * 64;
    int n0 = blockIdx.x * 64;

    float acc[4][4] = {};

    int am  = tid >> 2;        // 0..63
    int ak4 = (tid & 3) * 4;   // 0,4,8,12
    int bk  = tid >> 4;        // 0..15
    int bn4 = (tid & 15) * 4;  // 0..60

    for (int k0 = 0; k0 < K; k0 += 16) {
        int gm = m0 + am;
        float4 av = make_float4(0.f, 0.f, 0.f, 0.f);
        if (gm < M) av = *(const float4*)&A[(size_t)gm * K + k0 + ak4];
        As[ak4 + 0][am] = av.x;
        As[ak4 + 1][am] = av.y;
        As[ak4 + 2][am] = av.z;
        As[ak4 + 3][am] = av.w;
        float4 bv = *(const float4*)&B[(size_t)(k0 + bk) * N + n0 + bn4];
        *(float4*)&Bs[bk][bn4] = bv;
        __syncthreads();
#pragma unroll
        for (int kk = 0; kk < 16; kk++) {
            float a[4], b[4];
#pragma unroll
            for (int i = 0; i < 4; i++) a[i] = As[kk][ty * 4 + i];
#pragma unroll
            for (int j = 0; j < 4; j++) b[j] = Bs[kk][tx * 4 + j];
#pragma unroll
            for (int i = 0; i < 4; i++)
#pragma unroll
                for (int j = 0; j < 4; j++) acc[i][j] += a[i] * b[j];
        }
        __syncthreads();
    }
#pragma unroll
    for (int i = 0; i < 4; i++) {
        int gm = m0 + ty * 4 + i;
        if (gm < M) {
            float4 v = make_float4(acc[i][0], acc[i][1], acc[i][2], acc[i][3]);
            *(float4*)&C[(size_t)gm * N + n0 + tx * 4] = v;
        }
    }
}

// ---------------- aggregation 1 (F=256) ----------------

// agg1[r] = dinv[r]^2 * h1[r]  (self loop term; also initializes the buffer)
__global__ __launch_bounds__(256) void agg_init1(const float* __restrict__ h1,
                                                 const float* __restrict__ dinv,
                                                 float* __restrict__ agg1, int M) {
    int r = blockIdx.x;
    if (r >= M) return;
    int t = threadIdx.x;
    float d = dinv[r];
    agg1[(size_t)r * F_HID + t] = d * d * h1[(size_t)r * F_HID + t];
}

// per-edge scatter: agg1[dst] += dinv[src]*dinv[dst] * h1[src]
__global__ __launch_bounds__(256) void scatter1(const int* __restrict__ esrc,
                                                const int* __restrict__ edst,
                                                const float* __restrict__ dinv,
                                                const float* __restrict__ h1,
                                                float* __restrict__ agg1, int E) {
    int t = threadIdx.x;
    int e0 = blockIdx.x * 8;
#pragma unroll
    for (int i = 0; i < 8; i++) {
        int e = e0 + i;
        if (e < E) {
            int s = esrc[e], d = edst[e];
            float norm = dinv[s] * dinv[d];
            atomicAdd(&agg1[(size_t)d * F_HID + t],
                      norm * h1[(size_t)s * F_HID + t]);
        }
    }
}

// ---------------- GEMM2: h2 = relu(agg1 + b1) @ W2  (M x 256) @ (256 x 41) ----

__global__ __launch_bounds__(256) void gemm2(const float* __restrict__ agg1,
                                             const float* __restrict__ b1,
                                             const float* __restrict__ W2,
                                             float* __restrict__ h2, int M) {
    __shared__ float hs[4][F_HID];
    int r0 = blockIdx.x * 4;
    int t = threadIdx.x;
#pragma unroll
    for (int i = 0; i < 4; i++) {
        int r = r0 + i;
        float v = 0.f;
        if (r < M) v = fmaxf(agg1[(size_t)r * F_HID + t] + b1[t], 0.f);
        hs[i][t] = v;
    }
    __syncthreads();
    int w = t >> 6, lane = t & 63;
    int r = r0 + w;
    if (lane < N_CLS && r < M) {
        float sum = 0.f;
#pragma unroll 4
        for (int k = 0; k < F_HID; k++) sum += hs[w][k] * W2[k * N_CLS + lane];
        h2[(size_t)r * N_CLS + lane] = sum;
    }
}

// ---------------- aggregation 2 (F=41), accumulate into d_out ----------------

__global__ void agg_init2(const float* __restrict__ h2,
                          const float* __restrict__ dinv,
                          float* __restrict__ out, int M) {
    int r = blockIdx.x;
    if (r >= M) return;
    int lane = threadIdx.x;
    if (lane < N_CLS) {
        float d = dinv[r];
        out[(size_t)r * N_CLS + lane] = d * d * h2[(size_t)r * N_CLS + lane];
    }
}

__global__ __launch_bounds__(256) void scatter2(const int* __restrict__ esrc,
                                                const int* __restrict__ edst,
                                                const float* __restrict__ dinv,
                                                const float* __restrict__ h2,
                                                float* __restrict__ out, int E) {
    int t = threadIdx.x;
    int sub = t >> 6, lane = t & 63;
#pragma unroll
    for (int pass = 0; pass < 8; pass++) {
        int e = blockIdx.x * 32 + pass * 4 + sub;
        if (e < E && lane < N_CLS) {
            int s = esrc[e], d = edst[e];
            float norm = dinv[s] * dinv[d];
            atomicAdd(&out[(size_t)d * N_CLS + lane],
                      norm * h2[(size_t)s * N_CLS + lane]);
        }
    }
}

// ---------------- log_softmax (+b2), in place on d_out ----------------

__global__ __launch_bounds__(256) void logsoftmax(float* __restrict__ out,
                                                  const float* __restrict__ b2,
                                                  int M) {
    int t = threadIdx.x;
    int w = t >> 6, lane = t & 63;
    int r = blockIdx.x * 4 + w;
    if (r >= M) return;
    float v = -INFINITY;
    if (lane < N_CLS) v = out[(size_t)r * N_CLS + lane] + b2[lane];
    float m = v;
#pragma unroll
    for (int off = 32; off; off >>= 1) m = fmaxf(m, __shfl_xor(m, off));
    float ex = (lane < N_CLS) ? expf(v - m) : 0.f;
    float s = ex;
#pragma unroll
    for (int off = 32; off; off >>= 1) s += __shfl_xor(s, off);
    float ls = logf(s);
    if (lane < N_CLS) out[(size_t)r * N_CLS + lane] = v - m - ls;
}

// ---------------- launch ----------------

extern "C" void kernel_launch(void* const* d_in, const int* in_sizes, int n_in,
                              void* d_out, int out_size, void* d_ws, size_t ws_size,
                              hipStream_t stream) {
    const float* x  = (const float*)d_in[0];
    const int*   ei = (const int*)d_in[1];
    const float* W1 = (const float*)d_in[2];
    const float* b1 = (const float*)d_in[3];
    const float* W2 = (const float*)d_in[4];
    const float* b2 = (const float*)d_in[5];
    float* out = (float*)d_out;

    const int M = in_sizes[0] / F_IN;       // 100000
    const int E = in_sizes[1] / 2;          // 3200000
    const int* esrc = ei;
    const int* edst = ei + E;

    // workspace layout (bytes)
    char* ws = (char*)d_ws;
    float* dinv = (float*)(ws);                                  //   400,000 B
    float* h1   = (float*)(ws + 400000);                         // 102,400,000 B
    float* agg1 = (float*)(ws + 400000 + 102400000ull);          // 102,400,000 B
    float* h2   = (float*)(ws + 400000 + 204800000ull);          //  16,400,000 B

    // 1. degree + dinv
    init_deg<<<(M + 255) / 256, 256, 0, stream>>>(dinv, M);
    count_deg<<<(E + 255) / 256, 256, 0, stream>>>(edst, dinv, E);
    rsqrt_deg<<<(M + 255) / 256, 256, 0, stream>>>(dinv, M);

    // 2. h1 = x @ W1
    dim3 g1(F_HID / 64, (M + 63) / 64);
    sgemm1<<<g1, 256, 0, stream>>>(x, W1, h1, M);

    // 3. aggregate layer 1
    agg_init1<<<M, 256, 0, stream>>>(h1, dinv, agg1, M);
    scatter1<<<(E + 7) / 8, 256, 0, stream>>>(esrc, edst, dinv, h1, agg1, E);

    // 4. h2 = relu(agg1 + b1) @ W2
    gemm2<<<(M + 3) / 4, 256, 0, stream>>>(agg1, b1, W2, h2, M);

    // 5. aggregate layer 2 into d_out
    agg_init2<<<M, 64, 0, stream>>>(h2, dinv, out, M);
    scatter2<<<(E + 31) / 32, 256, 0, stream>>>(esrc, edst, dinv, h2, out, E);

    // 6. +b2, log_softmax in place
    logsoftmax<<<(M + 3) / 4, 256, 0, stream>>>(out, b2, M);
}

// Round 2
// 1916.587 us; speedup vs baseline: 2.1751x; 2.1751x over previous
//
#include <hip/hip_runtime.h>
#include <math.h>

// Problem constants (match reference file)
#define F_IN   512
#define F_HID  256
#define N_CLS  41

// ================= CSR build =================

__global__ void zero_int(int* p, int n) {
    int i = blockIdx.x * blockDim.x + threadIdx.x;
    if (i < n) p[i] = 0;
}

__global__ void count_int(const int* __restrict__ edst, int* cnt, int E) {
    int e = blockIdx.x * blockDim.x + threadIdx.x;
    if (e < E) atomicAdd(&cnt[edst[e]], 1);
}

__global__ void dinv_from_cnt(const int* __restrict__ cnt, float* dinv, int n) {
    int i = blockIdx.x * blockDim.x + threadIdx.x;
    if (i < n) dinv[i] = rsqrtf((float)cnt[i] + 1.0f);  // +1 self loop
}

// --- exclusive scan of rp[0..M) in place (3 kernels) ---

__global__ __launch_bounds__(256) void scanA(const int* __restrict__ rp,
                                             int* partial, int M) {
    __shared__ int s[256];
    int t = threadIdx.x;
    int i = blockIdx.x * 256 + t;
    s[t] = (i < M) ? rp[i] : 0;
    __syncthreads();
#pragma unroll
    for (int off = 128; off; off >>= 1) {
        if (t < off) s[t] += s[t + off];
        __syncthreads();
    }
    if (t == 0) partial[blockIdx.x] = s[0];
}

__global__ __launch_bounds__(512) void scanB(int* partial, int nb) {
    __shared__ int s[512];
    int t = threadIdx.x;
    int v = (t < nb) ? partial[t] : 0;
    s[t] = v;
    __syncthreads();
    for (int off = 1; off < 512; off <<= 1) {
        int x = (t >= off) ? s[t - off] : 0;
        __syncthreads();
        s[t] += x;
        __syncthreads();
    }
    if (t < nb) partial[t] = s[t] - v;  // exclusive
}

__global__ __launch_bounds__(256) void scanC(int* rp, const int* __restrict__ partial,
                                             int M) {
    __shared__ int s[256];
    int t = threadIdx.x;
    int i = blockIdx.x * 256 + t;
    int v = (i < M) ? rp[i] : 0;
    s[t] = v;
    __syncthreads();
    for (int off = 1; off < 256; off <<= 1) {
        int x = (t >= off) ? s[t - off] : 0;
        __syncthreads();
        s[t] += x;
        __syncthreads();
    }
    if (i < M) rp[i] = partial[blockIdx.x] + s[t] - v;  // exclusive prefix
}

// fill: rp[d] is the running cursor; post-fill rp[d] = inclusive end of row d.
// Row r segment = [ r? rp[r-1] : 0 , rp[r] ).
__global__ void fill_csr(const int* __restrict__ esrc, const int* __restrict__ edst,
                         int* rp, int* col, int E) {
    int e = blockIdx.x * blockDim.x + threadIdx.x;
    if (e < E) {
        int d = edst[e];
        int pos = atomicAdd(&rp[d], 1);
        col[pos] = esrc[e];
    }
}

// ================= SGEMM1: h1 = x @ W1  (M x 512) @ (512 x 256) =================
// 64x64 tile, BK=16, 256 threads, 4x4 per thread.

__global__ __launch_bounds__(256) void sgemm1(const float* __restrict__ A,
                                              const float* __restrict__ B,
                                              float* __restrict__ C, int M) {
    const int K = F_IN, N = F_HID;
    __shared__ float As[16][65];
    __shared__ float Bs[16][64];
    int tid = threadIdx.x;
    int tx = tid & 15, ty = tid >> 4;
    int m0 = blockIdx.y * 64;
    int n0 = blockIdx.x * 64;

    float acc[4][4] = {};

    int am  = tid >> 2;
    int ak4 = (tid & 3) * 4;
    int bk  = tid >> 4;
    int bn4 = (tid & 15) * 4;

    for (int k0 = 0; k0 < K; k0 += 16) {
        int gm = m0 + am;
        float4 av = make_float4(0.f, 0.f, 0.f, 0.f);
        if (gm < M) av = *(const float4*)&A[(size_t)gm * K + k0 + ak4];
        As[ak4 + 0][am] = av.x;
        As[ak4 + 1][am] = av.y;
        As[ak4 + 2][am] = av.z;
        As[ak4 + 3][am] = av.w;
        float4 bv = *(const float4*)&B[(size_t)(k0 + bk) * N + n0 + bn4];
        *(float4*)&Bs[bk][bn4] = bv;
        __syncthreads();
#pragma unroll
        for (int kk = 0; kk < 16; kk++) {
            float a[4], b[4];
#pragma unroll
            for (int i = 0; i < 4; i++) a[i] = As[kk][ty * 4 + i];
#pragma unroll
            for (int j = 0; j < 4; j++) b[j] = Bs[kk][tx * 4 + j];
#pragma unroll
            for (int i = 0; i < 4; i++)
#pragma unroll
                for (int j = 0; j < 4; j++) acc[i][j] += a[i] * b[j];
        }
        __syncthreads();
    }
#pragma unroll
    for (int i = 0; i < 4; i++) {
        int gm = m0 + ty * 4 + i;
        if (gm < M) {
            float4 v = make_float4(acc[i][0], acc[i][1], acc[i][2], acc[i][3]);
            *(float4*)&C[(size_t)gm * N + n0 + tx * 4] = v;
        }
    }
}

// ================= CSR aggregation layer 1 (F=256) + bias + ReLU =================
// One wave per dst node; lane holds float4 (4 features). Single write per node.
// act1[r] = relu( dinv[r] * (sum_e dinv[src]*h1[src] + dinv[r]*h1[r]) + b1 )

__global__ __launch_bounds__(256) void csr_agg1(const int* __restrict__ rp,
                                                const int* __restrict__ col,
                                                const float* __restrict__ dinv,
                                                const float* __restrict__ h1,
                                                const float* __restrict__ b1,
                                                float* __restrict__ act1, int M) {
    int w = threadIdx.x >> 6, lane = threadIdx.x & 63;
    int r = blockIdx.x * 4 + w;
    if (r >= M) return;
    int start = r ? rp[r - 1] : 0;
    int end = rp[r];
    float dr = dinv[r];

    const float4* h1v = (const float4*)h1;  // row stride 64 float4
    float4 v = h1v[(size_t)r * 64 + lane];
    float ax = dr * v.x, ay = dr * v.y, az = dr * v.z, aw = dr * v.w;

    for (int e = start; e < end; e++) {
        int s = col[e];          // wave-uniform broadcast load
        float ws = dinv[s];
        float4 hv = h1v[(size_t)s * 64 + lane];
        ax += ws * hv.x;
        ay += ws * hv.y;
        az += ws * hv.z;
        aw += ws * hv.w;
    }
    float4 bb = *(const float4*)&b1[lane * 4];
    float4 o;
    o.x = fmaxf(dr * ax + bb.x, 0.f);
    o.y = fmaxf(dr * ay + bb.y, 0.f);
    o.z = fmaxf(dr * az + bb.z, 0.f);
    o.w = fmaxf(dr * aw + bb.w, 0.f);
    ((float4*)act1)[(size_t)r * 64 + lane] = o;
}

// ================= GEMM2: h2 = act1 @ W2  (M x 256) @ (256 x 41) =================

__global__ __launch_bounds__(256) void gemm2(const float* __restrict__ act1,
                                             const float* __restrict__ W2,
                                             float* __restrict__ h2, int M) {
    __shared__ float hs[4][F_HID];
    int r0 = blockIdx.x * 4;
    int t = threadIdx.x;
    {   // vectorized load: 4 rows x 256 = 1024 floats = 256 threads x float4
        int row = t >> 6;
        int c4 = (t & 63) * 4;
        int r = r0 + row;
        float4 v = make_float4(0.f, 0.f, 0.f, 0.f);
        if (r < M) v = *(const float4*)&act1[(size_t)r * F_HID + c4];
        *(float4*)&hs[row][c4] = v;
    }
    __syncthreads();
    int w = t >> 6, lane = t & 63;
    int r = r0 + w;
    if (lane < N_CLS && r < M) {
        float sum = 0.f;
#pragma unroll 8
        for (int k = 0; k < F_HID; k++) sum += hs[w][k] * W2[k * N_CLS + lane];
        h2[(size_t)r * N_CLS + lane] = sum;
    }
}

// ========== CSR aggregation layer 2 (F=41) + b2 + log_softmax, into d_out ==========
// One wave per dst node; lanes 0..40 hold features.

__global__ __launch_bounds__(256) void csr_agg2_lsm(const int* __restrict__ rp,
                                                    const int* __restrict__ col,
                                                    const float* __restrict__ dinv,
                                                    const float* __restrict__ h2,
                                                    const float* __restrict__ b2,
                                                    float* __restrict__ out, int M) {
    int w = threadIdx.x >> 6, lane = threadIdx.x & 63;
    int r = blockIdx.x * 4 + w;
    if (r >= M) return;
    int start = r ? rp[r - 1] : 0;
    int end = rp[r];
    float dr = dinv[r];

    float acc = 0.f;
    if (lane < N_CLS) acc = dr * h2[(size_t)r * N_CLS + lane];
    for (int e = start; e < end; e++) {
        int s = col[e];          // wave-uniform
        float ws = dinv[s];
        if (lane < N_CLS) acc += ws * h2[(size_t)s * N_CLS + lane];
    }
    float v = (lane < N_CLS) ? dr * acc + b2[lane] : -INFINITY;

    // log_softmax across the wave's 41 live lanes
    float m = v;
#pragma unroll
    for (int off = 32; off; off >>= 1) m = fmaxf(m, __shfl_xor(m, off));
    float ex = (lane < N_CLS) ? expf(v - m) : 0.f;
    float s = ex;
#pragma unroll
    for (int off = 32; off; off >>= 1) s += __shfl_xor(s, off);
    float ls = logf(s);
    if (lane < N_CLS) out[(size_t)r * N_CLS + lane] = v - m - ls;
}

// ================= launch =================

extern "C" void kernel_launch(void* const* d_in, const int* in_sizes, int n_in,
                              void* d_out, int out_size, void* d_ws, size_t ws_size,
                              hipStream_t stream) {
    const float* x  = (const float*)d_in[0];
    const int*   ei = (const int*)d_in[1];
    const float* W1 = (const float*)d_in[2];
    const float* b1 = (const float*)d_in[3];
    const float* W2 = (const float*)d_in[4];
    const float* b2 = (const float*)d_in[5];
    float* out = (float*)d_out;

    const int M = in_sizes[0] / F_IN;       // 100000
    const int E = in_sizes[1] / 2;          // 3200000
    const int* esrc = ei;
    const int* edst = ei + E;

    const int NB = (M + 255) / 256;         // scan blocks (391)

    // workspace layout (bytes, 256-aligned)
    char* ws = (char*)d_ws;
    float* dinv    = (float*)(ws);                          //     400,128
    int*   rp      = (int*)  (ws + 400128);                 //     400,128
    int*   col     = (int*)  (ws + 800256);                 //  12,800,000
    int*   partial = (int*)  (ws + 13600256ull);            //       2,048
    float* h1      = (float*)(ws + 13602304ull);            // 102,400,000
    float* act1    = (float*)(ws + 116002304ull);           // 102,400,000
    float* h2      = h1;  // h1 dead after csr_agg1; reuse for h2 (16.4 MB)

    // --- CSR build + normalization ---
    zero_int<<<NB, 256, 0, stream>>>(rp, M);
    count_int<<<(E + 255) / 256, 256, 0, stream>>>(edst, rp, E);
    dinv_from_cnt<<<NB, 256, 0, stream>>>(rp, dinv, M);
    scanA<<<NB, 256, 0, stream>>>(rp, partial, M);
    scanB<<<1, 512, 0, stream>>>(partial, NB);
    scanC<<<NB, 256, 0, stream>>>(rp, partial, M);
    fill_csr<<<(E + 255) / 256, 256, 0, stream>>>(esrc, edst, rp, col, E);

    // --- layer 1 ---
    dim3 g1(F_HID / 64, (M + 63) / 64);
    sgemm1<<<g1, 256, 0, stream>>>(x, W1, h1, M);
    csr_agg1<<<(M + 3) / 4, 256, 0, stream>>>(rp, col, dinv, h1, b1, act1, M);

    // --- layer 2 ---
    gemm2<<<(M + 3) / 4, 256, 0, stream>>>(act1, W2, h2, M);
    csr_agg2_lsm<<<(M + 3) / 4, 256, 0, stream>>>(rp, col, dinv, h2, b2, out, M);
}

// Round 3
// 1541.674 us; speedup vs baseline: 2.7040x; 1.2432x over previous
//
#include <hip/hip_runtime.h>
#include <math.h>

// Problem constants (match reference file)
#define F_IN   512
#define F_HID  256
#define N_CLS  41

typedef __attribute__((ext_vector_type(8))) short     bf16x8;   // MFMA A/B frag
typedef __attribute__((ext_vector_type(8))) unsigned short u16x8;
typedef __attribute__((ext_vector_type(4))) float     f32x4;    // MFMA C/D frag

__device__ __forceinline__ float b2f(unsigned short u) {
    union { unsigned int i; float f; } v; v.i = ((unsigned int)u) << 16; return v.f;
}
__device__ __forceinline__ unsigned short f2b(float f) {  // RTN-even f32->bf16
    unsigned int u = __float_as_uint(f);
    u = (u + 0x7fffu + ((u >> 16) & 1u)) >> 16;
    return (unsigned short)u;
}

// ================= CSR build =================

__global__ void zero_int(int* p, int n) {
    int i = blockIdx.x * blockDim.x + threadIdx.x;
    if (i < n) p[i] = 0;
}

__global__ void count_int(const int* __restrict__ edst, int* cnt, int E) {
    int e = blockIdx.x * blockDim.x + threadIdx.x;
    if (e < E) atomicAdd(&cnt[edst[e]], 1);
}

__global__ void dinv_from_cnt(const int* __restrict__ cnt, float* dinv, int n) {
    int i = blockIdx.x * blockDim.x + threadIdx.x;
    if (i < n) dinv[i] = rsqrtf((float)cnt[i] + 1.0f);  // +1 self loop
}

// --- exclusive scan of rp[0..M) in place (3 kernels) ---

__global__ __launch_bounds__(256) void scanA(const int* __restrict__ rp,
                                             int* partial, int M) {
    __shared__ int s[256];
    int t = threadIdx.x;
    int i = blockIdx.x * 256 + t;
    s[t] = (i < M) ? rp[i] : 0;
    __syncthreads();
#pragma unroll
    for (int off = 128; off; off >>= 1) {
        if (t < off) s[t] += s[t + off];
        __syncthreads();
    }
    if (t == 0) partial[blockIdx.x] = s[0];
}

__global__ __launch_bounds__(512) void scanB(int* partial, int nb) {
    __shared__ int s[512];
    int t = threadIdx.x;
    int v = (t < nb) ? partial[t] : 0;
    s[t] = v;
    __syncthreads();
    for (int off = 1; off < 512; off <<= 1) {
        int x = (t >= off) ? s[t - off] : 0;
        __syncthreads();
        s[t] += x;
        __syncthreads();
    }
    if (t < nb) partial[t] = s[t] - v;  // exclusive
}

__global__ __launch_bounds__(256) void scanC(int* rp, const int* __restrict__ partial,
                                             int M) {
    __shared__ int s[256];
    int t = threadIdx.x;
    int i = blockIdx.x * 256 + t;
    int v = (i < M) ? rp[i] : 0;
    s[t] = v;
    __syncthreads();
    for (int off = 1; off < 256; off <<= 1) {
        int x = (t >= off) ? s[t - off] : 0;
        __syncthreads();
        s[t] += x;
        __syncthreads();
    }
    if (i < M) rp[i] = partial[blockIdx.x] + s[t] - v;  // exclusive prefix
}

// fill: rp[d] cursor; post-fill rp[d] = inclusive end of row d.
__global__ void fill_csr(const int* __restrict__ esrc, const int* __restrict__ edst,
                         int* rp, int* col, int E) {
    int e = blockIdx.x * blockDim.x + threadIdx.x;
    if (e < E) {
        int d = edst[e];
        int pos = atomicAdd(&rp[d], 1);
        col[pos] = esrc[e];
    }
}

// ================= W1 transpose + bf16 convert: W1t[n][k] = bf16(W1[k][n]) ======

__global__ __launch_bounds__(256) void cvt_W1t(const float* __restrict__ W1,
                                               unsigned short* __restrict__ W1t) {
    int n = blockIdx.x;  // 0..255
    for (int k = threadIdx.x; k < F_IN; k += 256)
        W1t[n * F_IN + k] = f2b(W1[(size_t)k * F_HID + n]);
}

// ================= MFMA GEMM1: h1 = bf16(x) @ bf16(W1)  (M x 512)@(512 x 256) ===
// 128x128 tile, BK=32, 4 waves x (4x4 16x16x32 tiles). A converted f32->bf16 in
// staging; B staged from pre-transposed W1t. Output h1 in bf16.

__global__ __launch_bounds__(256) void mfma_gemm1(const float* __restrict__ A,
                                                  const unsigned short* __restrict__ Bt,
                                                  unsigned short* __restrict__ H1,
                                                  int M) {
    __shared__ unsigned short As[128 * 40];  // [m][k], +8 pad (80 B rows: 2-way free)
    __shared__ unsigned short Bs[128 * 40];  // [n][k]
    int tid = threadIdx.x;
    int wave = tid >> 6, lane = tid & 63;
    int quad = lane >> 4, l15 = lane & 15;
    int m0 = blockIdx.y * 128, n0 = blockIdx.x * 128;
    int wm = (wave & 1) * 64, wn = (wave >> 1) * 64;

    f32x4 acc[4][4] = {};

    int ar = tid >> 1, ah = tid & 1;   // A: row, k-half (16 f32)
    int bn = tid >> 1, bc = tid & 1;   // B: row(n), chunk parity

    for (int k0 = 0; k0 < F_IN; k0 += 32) {
        // ---- stage A (f32 -> bf16) ----
        {
            int gm = m0 + ar;
            float4 v0, v1, v2, v3;
            if (gm < M) {
                const float4* ap = (const float4*)&A[(size_t)gm * F_IN + k0 + ah * 16];
                v0 = ap[0]; v1 = ap[1]; v2 = ap[2]; v3 = ap[3];
            } else {
                v0 = v1 = v2 = v3 = make_float4(0.f, 0.f, 0.f, 0.f);
            }
            u16x8 w0, w1;
            w0[0]=f2b(v0.x); w0[1]=f2b(v0.y); w0[2]=f2b(v0.z); w0[3]=f2b(v0.w);
            w0[4]=f2b(v1.x); w0[5]=f2b(v1.y); w0[6]=f2b(v1.z); w0[7]=f2b(v1.w);
            w1[0]=f2b(v2.x); w1[1]=f2b(v2.y); w1[2]=f2b(v2.z); w1[3]=f2b(v2.w);
            w1[4]=f2b(v3.x); w1[5]=f2b(v3.y); w1[6]=f2b(v3.z); w1[7]=f2b(v3.w);
            *(u16x8*)&As[ar * 40 + ah * 16]     = w0;
            *(u16x8*)&As[ar * 40 + ah * 16 + 8] = w1;
        }
        // ---- stage B (already bf16) ----
        {
            const unsigned short* bp = &Bt[(size_t)(n0 + bn) * F_IN + k0];
            *(u16x8*)&Bs[bn * 40 + bc * 8]        = *(const u16x8*)(bp + bc * 8);
            *(u16x8*)&Bs[bn * 40 + (bc + 2) * 8]  = *(const u16x8*)(bp + bc * 8 + 16);
        }
        __syncthreads();
        // ---- fragments + MFMA ----
        bf16x8 af[4], bfr[4];
#pragma unroll
        for (int i = 0; i < 4; i++)
            af[i] = *(const bf16x8*)&As[(wm + i * 16 + l15) * 40 + quad * 8];
#pragma unroll
        for (int j = 0; j < 4; j++)
            bfr[j] = *(const bf16x8*)&Bs[(wn + j * 16 + l15) * 40 + quad * 8];
#pragma unroll
        for (int i = 0; i < 4; i++)
#pragma unroll
            for (int j = 0; j < 4; j++)
                acc[i][j] = __builtin_amdgcn_mfma_f32_16x16x32_bf16(
                    af[i], bfr[j], acc[i][j], 0, 0, 0);
        __syncthreads();
    }
    // ---- epilogue: C layout col=lane&15, row=quad*4+reg ----
#pragma unroll
    for (int i = 0; i < 4; i++) {
#pragma unroll
        for (int rr = 0; rr < 4; rr++) {
            int gm = m0 + wm + i * 16 + quad * 4 + rr;
            if (gm < M) {
#pragma unroll
                for (int j = 0; j < 4; j++) {
                    int gn = n0 + wn + j * 16 + l15;
                    H1[(size_t)gm * F_HID + gn] = f2b(acc[i][j][rr]);
                }
            }
        }
    }
}

// ============ CSR aggregation layer 1 (F=256, bf16 in/out) + bias + ReLU ========
// One wave per dst node; lane holds 4 bf16 feats. f32 accumulate.

__global__ __launch_bounds__(256) void csr_agg1(const int* __restrict__ rp,
                                                const int* __restrict__ col,
                                                const float* __restrict__ dinv,
                                                const unsigned short* __restrict__ h1,
                                                const float* __restrict__ b1,
                                                unsigned short* __restrict__ act1,
                                                int M) {
    int w = threadIdx.x >> 6, lane = threadIdx.x & 63;
    int r = blockIdx.x * 4 + w;
    if (r >= M) return;
    int start = r ? rp[r - 1] : 0;
    int end = rp[r];
    float dr = dinv[r];

    const ushort4* hv = (const ushort4*)h1;  // node stride 64 ushort4
    ushort4 v = hv[(size_t)r * 64 + lane];
    float ax = dr * b2f(v.x), ay = dr * b2f(v.y), az = dr * b2f(v.z), aw = dr * b2f(v.w);

    for (int e = start; e < end; e++) {
        int s = col[e];          // wave-uniform broadcast
        float ws = dinv[s];
        ushort4 q = hv[(size_t)s * 64 + lane];
        ax += ws * b2f(q.x);
        ay += ws * b2f(q.y);
        az += ws * b2f(q.z);
        aw += ws * b2f(q.w);
    }
    float4 bb = *(const float4*)&b1[lane * 4];
    ushort4 o;
    o.x = f2b(fmaxf(dr * ax + bb.x, 0.f));
    o.y = f2b(fmaxf(dr * ay + bb.y, 0.f));
    o.z = f2b(fmaxf(dr * az + bb.z, 0.f));
    o.w = f2b(fmaxf(dr * aw + bb.w, 0.f));
    ((ushort4*)act1)[(size_t)r * 64 + lane] = o;
}

// ========= GEMM2: h2 = act1 @ W2  (M x 256 bf16) @ (256 x 41 f32) ==============

__global__ __launch_bounds__(256) void gemm2(const unsigned short* __restrict__ act1,
                                             const float* __restrict__ W2,
                                             float* __restrict__ h2, int M) {
    __shared__ float hs[4][F_HID];
    int r0 = blockIdx.x * 4;
    int t = threadIdx.x;
    {
        int row = t >> 6;
        int c4 = (t & 63) * 4;
        int r = r0 + row;
        float4 v = make_float4(0.f, 0.f, 0.f, 0.f);
        if (r < M) {
            ushort4 q = *(const ushort4*)&act1[(size_t)r * F_HID + c4];
            v = make_float4(b2f(q.x), b2f(q.y), b2f(q.z), b2f(q.w));
        }
        *(float4*)&hs[row][c4] = v;
    }
    __syncthreads();
    int w = t >> 6, lane = t & 63;
    int r = r0 + w;
    if (lane < N_CLS && r < M) {
        float sum = 0.f;
#pragma unroll 8
        for (int k = 0; k < F_HID; k++) sum += hs[w][k] * W2[k * N_CLS + lane];
        h2[(size_t)r * N_CLS + lane] = sum;
    }
}

// ===== CSR aggregation layer 2 (F=41) + b2 + log_softmax, into d_out ===========

__global__ __launch_bounds__(256) void csr_agg2_lsm(const int* __restrict__ rp,
                                                    const int* __restrict__ col,
                                                    const float* __restrict__ dinv,
                                                    const float* __restrict__ h2,
                                                    const float* __restrict__ b2,
                                                    float* __restrict__ out, int M) {
    int w = threadIdx.x >> 6, lane = threadIdx.x & 63;
    int r = blockIdx.x * 4 + w;
    if (r >= M) return;
    int start = r ? rp[r - 1] : 0;
    int end = rp[r];
    float dr = dinv[r];

    float acc = 0.f;
    if (lane < N_CLS) acc = dr * h2[(size_t)r * N_CLS + lane];
    for (int e = start; e < end; e++) {
        int s = col[e];          // wave-uniform
        float ws = dinv[s];
        if (lane < N_CLS) acc += ws * h2[(size_t)s * N_CLS + lane];
    }
    float v = (lane < N_CLS) ? dr * acc + b2[lane] : -INFINITY;

    float m = v;
#pragma unroll
    for (int off = 32; off; off >>= 1) m = fmaxf(m, __shfl_xor(m, off));
    float ex = (lane < N_CLS) ? expf(v - m) : 0.f;
    float s = ex;
#pragma unroll
    for (int off = 32; off; off >>= 1) s += __shfl_xor(s, off);
    float ls = logf(s);
    if (lane < N_CLS) out[(size_t)r * N_CLS + lane] = v - m - ls;
}

// ================= launch =================

extern "C" void kernel_launch(void* const* d_in, const int* in_sizes, int n_in,
                              void* d_out, int out_size, void* d_ws, size_t ws_size,
                              hipStream_t stream) {
    const float* x  = (const float*)d_in[0];
    const int*   ei = (const int*)d_in[1];
    const float* W1 = (const float*)d_in[2];
    const float* b1 = (const float*)d_in[3];
    const float* W2 = (const float*)d_in[4];
    const float* b2 = (const float*)d_in[5];
    float* out = (float*)d_out;

    const int M = in_sizes[0] / F_IN;       // 100000
    const int E = in_sizes[1] / 2;          // 3200000
    const int* esrc = ei;
    const int* edst = ei + E;

    const int NB = (M + 255) / 256;         // 391 scan blocks

    // workspace layout (bytes, 256-aligned)
    char* ws = (char*)d_ws;
    float*          dinv    = (float*)(ws);                       //     400,128
    int*            rp      = (int*)  (ws +    400128);           //     400,128
    int*            col     = (int*)  (ws +    800256);           //  12,800,000
    int*            partial = (int*)  (ws +  13600256ull);        //       2,048
    unsigned short* W1t     = (unsigned short*)(ws + 13602304ull);//     262,144
    unsigned short* h1      = (unsigned short*)(ws + 13864448ull);//  51,200,000
    unsigned short* act1    = (unsigned short*)(ws + 65064448ull);//  51,200,000
    float*          h2      = (float*)(ws + 116264448ull);        //  16,400,000

    // --- CSR build + normalization ---
    zero_int<<<NB, 256, 0, stream>>>(rp, M);
    count_int<<<(E + 255) / 256, 256, 0, stream>>>(edst, rp, E);
    dinv_from_cnt<<<NB, 256, 0, stream>>>(rp, dinv, M);
    scanA<<<NB, 256, 0, stream>>>(rp, partial, M);
    scanB<<<1, 512, 0, stream>>>(partial, NB);
    scanC<<<NB, 256, 0, stream>>>(rp, partial, M);
    fill_csr<<<(E + 255) / 256, 256, 0, stream>>>(esrc, edst, rp, col, E);

    // --- layer 1 ---
    cvt_W1t<<<F_HID, 256, 0, stream>>>(W1, W1t);
    dim3 g1(F_HID / 128, (M + 127) / 128);
    mfma_gemm1<<<g1, 256, 0, stream>>>(x, W1t, h1, M);
    csr_agg1<<<(M + 3) / 4, 256, 0, stream>>>(rp, col, dinv, h1, b1, act1, M);

    // --- layer 2 ---
    gemm2<<<(M + 3) / 4, 256, 0, stream>>>(act1, W2, h2, M);
    csr_agg2_lsm<<<(M + 3) / 4, 256, 0, stream>>>(rp, col, dinv, h2, b2, out, M);
}

// Round 4
// 1103.660 us; speedup vs baseline: 3.7772x; 1.3969x over previous
//
#include <hip/hip_runtime.h>
#include <math.h>

// Problem constants (match reference file)
#define F_IN   512
#define F_HID  256
#define N_CLS  41

typedef __attribute__((ext_vector_type(8))) short     bf16x8;   // MFMA A/B frag
typedef __attribute__((ext_vector_type(8))) unsigned short u16x8;
typedef __attribute__((ext_vector_type(4))) float     f32x4;    // MFMA C/D frag

__device__ __forceinline__ float b2f(unsigned short u) {
    union { unsigned int i; float f; } v; v.i = ((unsigned int)u) << 16; return v.f;
}
__device__ __forceinline__ unsigned short f2b(float f) {  // RTN-even f32->bf16
    unsigned int u = __float_as_uint(f);
    u = (u + 0x7fffu + ((u >> 16) & 1u)) >> 16;
    return (unsigned short)u;
}

// ================= CSR build =================

__global__ void zero_int(int* p, int n) {
    int i = blockIdx.x * blockDim.x + threadIdx.x;
    if (i < n) p[i] = 0;
}

__global__ void count_int(const int* __restrict__ edst, int* cnt, int E) {
    int e0 = (blockIdx.x * blockDim.x + threadIdx.x) * 4;
    if (e0 + 4 <= E) {
        int4 d = *(const int4*)&edst[e0];
        atomicAdd(&cnt[d.x], 1);
        atomicAdd(&cnt[d.y], 1);
        atomicAdd(&cnt[d.z], 1);
        atomicAdd(&cnt[d.w], 1);
    } else {
        for (int e = e0; e < E; e++) atomicAdd(&cnt[edst[e]], 1);
    }
}

__global__ void dinv_from_cnt(const int* __restrict__ cnt, float* dinv, int n) {
    int i = blockIdx.x * blockDim.x + threadIdx.x;
    if (i < n) dinv[i] = rsqrtf((float)cnt[i] + 1.0f);  // +1 self loop
}

// --- exclusive scan of rp[0..M) in place (3 kernels) ---

__global__ __launch_bounds__(256) void scanA(const int* __restrict__ rp,
                                             int* partial, int M) {
    __shared__ int s[256];
    int t = threadIdx.x;
    int i = blockIdx.x * 256 + t;
    s[t] = (i < M) ? rp[i] : 0;
    __syncthreads();
#pragma unroll
    for (int off = 128; off; off >>= 1) {
        if (t < off) s[t] += s[t + off];
        __syncthreads();
    }
    if (t == 0) partial[blockIdx.x] = s[0];
}

__global__ __launch_bounds__(512) void scanB(int* partial, int nb) {
    __shared__ int s[512];
    int t = threadIdx.x;
    int v = (t < nb) ? partial[t] : 0;
    s[t] = v;
    __syncthreads();
    for (int off = 1; off < 512; off <<= 1) {
        int x = (t >= off) ? s[t - off] : 0;
        __syncthreads();
        s[t] += x;
        __syncthreads();
    }
    if (t < nb) partial[t] = s[t] - v;  // exclusive
}

__global__ __launch_bounds__(256) void scanC(int* rp, const int* __restrict__ partial,
                                             int M) {
    __shared__ int s[256];
    int t = threadIdx.x;
    int i = blockIdx.x * 256 + t;
    int v = (i < M) ? rp[i] : 0;
    s[t] = v;
    __syncthreads();
    for (int off = 1; off < 256; off <<= 1) {
        int x = (t >= off) ? s[t - off] : 0;
        __syncthreads();
        s[t] += x;
        __syncthreads();
    }
    if (i < M) rp[i] = partial[blockIdx.x] + s[t] - v;  // exclusive prefix
}

// fill: rp[d] cursor; post-fill rp[d] = inclusive end of row d.
__global__ void fill_csr(const int* __restrict__ esrc, const int* __restrict__ edst,
                         int* rp, int* col, int E) {
    int e0 = (blockIdx.x * blockDim.x + threadIdx.x) * 4;
    if (e0 + 4 <= E) {
        int4 d = *(const int4*)&edst[e0];
        int4 s = *(const int4*)&esrc[e0];
        col[atomicAdd(&rp[d.x], 1)] = s.x;
        col[atomicAdd(&rp[d.y], 1)] = s.y;
        col[atomicAdd(&rp[d.z], 1)] = s.z;
        col[atomicAdd(&rp[d.w], 1)] = s.w;
    } else {
        for (int e = e0; e < E; e++) {
            int pos = atomicAdd(&rp[edst[e]], 1);
            col[pos] = esrc[e];
        }
    }
}

// ========== weight prep: W1t[n][k]=bf16(W1[k][n]); W2t[n][k]=bf16(W2[k][n]) =====

__global__ __launch_bounds__(256) void cvt_W1t(const float* __restrict__ W1,
                                               unsigned short* __restrict__ W1t) {
    int n = blockIdx.x;  // 0..255
    for (int k = threadIdx.x; k < F_IN; k += 256)
        W1t[n * F_IN + k] = f2b(W1[(size_t)k * F_HID + n]);
}

__global__ __launch_bounds__(256) void cvt_W2t(const float* __restrict__ W2,
                                               unsigned short* __restrict__ W2t) {
    int n = blockIdx.x;   // 0..47 (padded)
    int k = threadIdx.x;  // 0..255
    W2t[n * F_HID + k] = (n < N_CLS) ? f2b(W2[(size_t)k * N_CLS + n])
                                     : (unsigned short)0;
}

// ====== MFMA GEMM1: h1s = dinv[m] * (bf16(x) @ bf16(W1))  (M x 512)@(512 x 256) ==
// 128x256 tile (full N in one block), BK=32, 512 threads = 8 waves (2x4 of 64x64).
// x read ONCE. Output pre-scaled by dinv[row], bf16.

__global__ __launch_bounds__(512) void mfma_gemm1(const float* __restrict__ A,
                                                  const unsigned short* __restrict__ Bt,
                                                  const float* __restrict__ dinv,
                                                  unsigned short* __restrict__ H1,
                                                  int M) {
    __shared__ unsigned short As[128 * 40];  // [m][k], row 40 shorts (pad)
    __shared__ unsigned short Bs[256 * 40];  // [n][k]
    int tid = threadIdx.x;
    int wave = tid >> 6, lane = tid & 63;
    int quad = lane >> 4, l15 = lane & 15;
    int m0 = blockIdx.x * 128;
    int wm = (wave & 1) * 64, wn = (wave >> 1) * 64;

    f32x4 acc[4][4] = {};

    int ar = tid >> 2, aq = tid & 3;   // A: row 0..127, 8-float quarter
    int bn = tid >> 1, bc = tid & 1;   // B: row(n) 0..255, chunk parity

    for (int k0 = 0; k0 < F_IN; k0 += 32) {
        // ---- stage A (f32 -> bf16) ----
        {
            int gm = m0 + ar;
            float4 v0, v1;
            if (gm < M) {
                const float4* ap = (const float4*)&A[(size_t)gm * F_IN + k0 + aq * 8];
                v0 = ap[0]; v1 = ap[1];
            } else {
                v0 = v1 = make_float4(0.f, 0.f, 0.f, 0.f);
            }
            u16x8 w;
            w[0]=f2b(v0.x); w[1]=f2b(v0.y); w[2]=f2b(v0.z); w[3]=f2b(v0.w);
            w[4]=f2b(v1.x); w[5]=f2b(v1.y); w[6]=f2b(v1.z); w[7]=f2b(v1.w);
            *(u16x8*)&As[ar * 40 + aq * 8] = w;
        }
        // ---- stage B (already bf16) ----
        {
            const unsigned short* bp = &Bt[(size_t)bn * F_IN + k0];
            *(u16x8*)&Bs[bn * 40 + bc * 8]       = *(const u16x8*)(bp + bc * 8);
            *(u16x8*)&Bs[bn * 40 + (bc + 2) * 8] = *(const u16x8*)(bp + bc * 8 + 16);
        }
        __syncthreads();
        bf16x8 af[4], bfr[4];
#pragma unroll
        for (int i = 0; i < 4; i++)
            af[i] = *(const bf16x8*)&As[(wm + i * 16 + l15) * 40 + quad * 8];
#pragma unroll
        for (int j = 0; j < 4; j++)
            bfr[j] = *(const bf16x8*)&Bs[(wn + j * 16 + l15) * 40 + quad * 8];
#pragma unroll
        for (int i = 0; i < 4; i++)
#pragma unroll
            for (int j = 0; j < 4; j++)
                acc[i][j] = __builtin_amdgcn_mfma_f32_16x16x32_bf16(
                    af[i], bfr[j], acc[i][j], 0, 0, 0);
        __syncthreads();
    }
    // ---- epilogue: C layout col=l15, row=quad*4+rr; pre-scale by dinv[row] ----
#pragma unroll
    for (int i = 0; i < 4; i++) {
#pragma unroll
        for (int rr = 0; rr < 4; rr++) {
            int gm = m0 + wm + i * 16 + quad * 4 + rr;
            if (gm < M) {
                float dv = dinv[gm];
#pragma unroll
                for (int j = 0; j < 4; j++) {
                    int gn = wn + j * 16 + l15;
                    H1[(size_t)gm * F_HID + gn] = f2b(dv * acc[i][j][rr]);
                }
            }
        }
    }
}

// ======= CSR aggregation layer 1 (F=256, bf16, dinv-prescaled) + bias + ReLU =====
// One wave per dst node; lane holds 4 bf16 feats; edge loop unrolled x8 for MLP.
// act1[r] = relu( dinv[r] * (sum_e h1s[col] + h1s[r]) + b1 )

__global__ __launch_bounds__(256) void csr_agg1(const int* __restrict__ rp,
                                                const int* __restrict__ col,
                                                const float* __restrict__ dinv,
                                                const unsigned short* __restrict__ h1,
                                                const float* __restrict__ b1,
                                                unsigned short* __restrict__ act1,
                                                int M) {
    int w = threadIdx.x >> 6, lane = threadIdx.x & 63;
    int r = blockIdx.x * 4 + w;
    if (r >= M) return;
    int start = r ? rp[r - 1] : 0;
    int end = rp[r];
    float dr = dinv[r];

    const ushort4* hv = (const ushort4*)h1;  // node stride 64 ushort4
    ushort4 v = hv[(size_t)r * 64 + lane];   // self term (already dinv[r]-scaled)
    float ax = b2f(v.x), ay = b2f(v.y), az = b2f(v.z), aw = b2f(v.w);

    int e = start;
    for (; e + 8 <= end; e += 8) {
        int s0 = col[e],     s1 = col[e + 1], s2 = col[e + 2], s3 = col[e + 3];
        int s4 = col[e + 4], s5 = col[e + 5], s6 = col[e + 6], s7 = col[e + 7];
        ushort4 q0 = hv[(size_t)s0 * 64 + lane];
        ushort4 q1 = hv[(size_t)s1 * 64 + lane];
        ushort4 q2 = hv[(size_t)s2 * 64 + lane];
        ushort4 q3 = hv[(size_t)s3 * 64 + lane];
        ushort4 q4 = hv[(size_t)s4 * 64 + lane];
        ushort4 q5 = hv[(size_t)s5 * 64 + lane];
        ushort4 q6 = hv[(size_t)s6 * 64 + lane];
        ushort4 q7 = hv[(size_t)s7 * 64 + lane];
        ax += ((b2f(q0.x) + b2f(q1.x)) + (b2f(q2.x) + b2f(q3.x)))
            + ((b2f(q4.x) + b2f(q5.x)) + (b2f(q6.x) + b2f(q7.x)));
        ay += ((b2f(q0.y) + b2f(q1.y)) + (b2f(q2.y) + b2f(q3.y)))
            + ((b2f(q4.y) + b2f(q5.y)) + (b2f(q6.y) + b2f(q7.y)));
        az += ((b2f(q0.z) + b2f(q1.z)) + (b2f(q2.z) + b2f(q3.z)))
            + ((b2f(q4.z) + b2f(q5.z)) + (b2f(q6.z) + b2f(q7.z)));
        aw += ((b2f(q0.w) + b2f(q1.w)) + (b2f(q2.w) + b2f(q3.w)))
            + ((b2f(q4.w) + b2f(q5.w)) + (b2f(q6.w) + b2f(q7.w)));
    }
    for (; e < end; e++) {
        ushort4 q = hv[(size_t)col[e] * 64 + lane];
        ax += b2f(q.x); ay += b2f(q.y); az += b2f(q.z); aw += b2f(q.w);
    }
    float4 bb = *(const float4*)&b1[lane * 4];
    ushort4 o;
    o.x = f2b(fmaxf(dr * ax + bb.x, 0.f));
    o.y = f2b(fmaxf(dr * ay + bb.y, 0.f));
    o.z = f2b(fmaxf(dr * az + bb.z, 0.f));
    o.w = f2b(fmaxf(dr * aw + bb.w, 0.f));
    ((ushort4*)act1)[(size_t)r * 64 + lane] = o;
}

// ===== MFMA GEMM2: h2s = dinv[m] * (act1 @ bf16(W2))  (M x 256)@(256 x 48pad) ===
// One wave per 16 rows; A frags straight from global (no LDS); W2t from L2.

__global__ __launch_bounds__(256) void mfma_gemm2(const unsigned short* __restrict__ act1,
                                                  const unsigned short* __restrict__ W2t,
                                                  const float* __restrict__ dinv,
                                                  float* __restrict__ h2, int M) {
    int wave = threadIdx.x >> 6, lane = threadIdx.x & 63;
    int quad = lane >> 4, l15 = lane & 15;
    int r0 = (blockIdx.x * 4 + wave) * 16;
    if (r0 >= M) return;

    f32x4 acc[3] = {};
    const unsigned short* arow = &act1[(size_t)(r0 + l15) * F_HID];
#pragma unroll
    for (int kt = 0; kt < F_HID; kt += 32) {
        bf16x8 af = *(const bf16x8*)&arow[kt + quad * 8];
#pragma unroll
        for (int j = 0; j < 3; j++) {
            bf16x8 bf = *(const bf16x8*)&W2t[(size_t)(j * 16 + l15) * F_HID + kt + quad * 8];
            acc[j] = __builtin_amdgcn_mfma_f32_16x16x32_bf16(af, bf, acc[j], 0, 0, 0);
        }
    }
    // C layout: col = l15 + j*16, row = quad*4 + rr; pre-scale by dinv[row]
#pragma unroll
    for (int j = 0; j < 3; j++) {
        int c = j * 16 + l15;
        if (c < N_CLS) {
#pragma unroll
            for (int rr = 0; rr < 4; rr++) {
                int r = r0 + quad * 4 + rr;
                h2[(size_t)r * N_CLS + c] = dinv[r] * acc[j][rr];
            }
        }
    }
}

// ===== CSR aggregation layer 2 (F=41, dinv-prescaled) + b2 + log_softmax ========

__global__ __launch_bounds__(256) void csr_agg2_lsm(const int* __restrict__ rp,
                                                    const int* __restrict__ col,
                                                    const float* __restrict__ dinv,
                                                    const float* __restrict__ h2,
                                                    const float* __restrict__ b2,
                                                    float* __restrict__ out, int M) {
    int w = threadIdx.x >> 6, lane = threadIdx.x & 63;
    int r = blockIdx.x * 4 + w;
    if (r >= M) return;
    int start = r ? rp[r - 1] : 0;
    int end = rp[r];
    float dr = dinv[r];

    float acc = 0.f;
    if (lane < N_CLS) acc = h2[(size_t)r * N_CLS + lane];  // self (prescaled)
    int e = start;
    for (; e + 4 <= end; e += 4) {
        int s0 = col[e], s1 = col[e + 1], s2 = col[e + 2], s3 = col[e + 3];
        if (lane < N_CLS) {
            float a0 = h2[(size_t)s0 * N_CLS + lane];
            float a1 = h2[(size_t)s1 * N_CLS + lane];
            float a2 = h2[(size_t)s2 * N_CLS + lane];
            float a3 = h2[(size_t)s3 * N_CLS + lane];
            acc += (a0 + a1) + (a2 + a3);
        }
    }
    for (; e < end; e++) {
        if (lane < N_CLS) acc += h2[(size_t)col[e] * N_CLS + lane];
    }
    float v = (lane < N_CLS) ? dr * acc + b2[lane] : -INFINITY;

    float m = v;
#pragma unroll
    for (int off = 32; off; off >>= 1) m = fmaxf(m, __shfl_xor(m, off));
    float ex = (lane < N_CLS) ? expf(v - m) : 0.f;
    float s = ex;
#pragma unroll
    for (int off = 32; off; off >>= 1) s += __shfl_xor(s, off);
    float ls = logf(s);
    if (lane < N_CLS) out[(size_t)r * N_CLS + lane] = v - m - ls;
}

// ================= launch =================

extern "C" void kernel_launch(void* const* d_in, const int* in_sizes, int n_in,
                              void* d_out, int out_size, void* d_ws, size_t ws_size,
                              hipStream_t stream) {
    const float* x  = (const float*)d_in[0];
    const int*   ei = (const int*)d_in[1];
    const float* W1 = (const float*)d_in[2];
    const float* b1 = (const float*)d_in[3];
    const float* W2 = (const float*)d_in[4];
    const float* b2 = (const float*)d_in[5];
    float* out = (float*)d_out;

    const int M = in_sizes[0] / F_IN;       // 100000
    const int E = in_sizes[1] / 2;          // 3200000
    const int* esrc = ei;
    const int* edst = ei + E;

    const int NB = (M + 255) / 256;         // 391 scan blocks

    // workspace layout (bytes, 16-aligned)
    char* ws = (char*)d_ws;
    float*          dinv    = (float*)(ws);                        //     400,128
    int*            rp      = (int*)  (ws +    400128);            //     400,128
    int*            col     = (int*)  (ws +    800256);            //  12,800,000
    int*            partial = (int*)  (ws +  13600256ull);         //       2,048
    unsigned short* W1t     = (unsigned short*)(ws + 13602304ull); //     262,144
    unsigned short* W2t     = (unsigned short*)(ws + 13864448ull); //      24,576
    unsigned short* h1      = (unsigned short*)(ws + 13889024ull); //  51,200,000
    unsigned short* act1    = (unsigned short*)(ws + 65089024ull); //  51,200,000
    float*          h2      = (float*)(ws + 116289024ull);         //  16,400,000

    // --- CSR build + normalization ---
    zero_int<<<NB, 256, 0, stream>>>(rp, M);
    count_int<<<(E / 4 + 255) / 256, 256, 0, stream>>>(edst, rp, E);
    dinv_from_cnt<<<NB, 256, 0, stream>>>(rp, dinv, M);
    scanA<<<NB, 256, 0, stream>>>(rp, partial, M);
    scanB<<<1, 512, 0, stream>>>(partial, NB);
    scanC<<<NB, 256, 0, stream>>>(rp, partial, M);
    fill_csr<<<(E / 4 + 255) / 256, 256, 0, stream>>>(esrc, edst, rp, col, E);

    // --- weight prep ---
    cvt_W1t<<<F_HID, 256, 0, stream>>>(W1, W1t);
    cvt_W2t<<<48, 256, 0, stream>>>(W2, W2t);

    // --- layer 1 ---
    mfma_gemm1<<<(M + 127) / 128, 512, 0, stream>>>(x, W1t, dinv, h1, M);
    csr_agg1<<<(M + 3) / 4, 256, 0, stream>>>(rp, col, dinv, h1, b1, act1, M);

    // --- layer 2 ---
    mfma_gemm2<<<(M / 16 + 3) / 4, 256, 0, stream>>>(act1, W2t, dinv, h2, M);
    csr_agg2_lsm<<<(M + 3) / 4, 256, 0, stream>>>(rp, col, dinv, h2, b2, out, M);
}

// Round 5
// 949.220 us; speedup vs baseline: 4.3917x; 1.1627x over previous
//
#include <hip/hip_runtime.h>
#include <math.h>

// Problem constants (match reference file)
#define F_IN   512
#define F_HID  256
#define N_CLS  41

#define CHUNK  16384         // edges per workgroup in hist/scatter passes
#define MAXBK  3200          // LDS capacity for bucket arrays (NBK = ceil(M/32) = 3125)
#define PKMASK 0x1FFFF       // low 17 bits = src (M < 131072)

typedef __attribute__((ext_vector_type(8))) short     bf16x8;   // MFMA A/B frag
typedef __attribute__((ext_vector_type(8))) unsigned short u16x8;
typedef __attribute__((ext_vector_type(4))) float     f32x4;    // MFMA C/D frag

__device__ __forceinline__ float b2f(unsigned short u) {
    union { unsigned int i; float f; } v; v.i = ((unsigned int)u) << 16; return v.f;
}
__device__ __forceinline__ unsigned short f2b(float f) {  // RTN-even f32->bf16
    unsigned int u = __float_as_uint(f);
    u = (u + 0x7fffu + ((u >> 16) & 1u)) >> 16;
    return (unsigned short)u;
}

// ================= CSR build, atomic-storm-free =================
// Pass 1: per-WG LDS histogram over dst buckets (bucket = 32 nodes).
__global__ __launch_bounds__(256) void hist_pass(const int* __restrict__ edst,
                                                 int* __restrict__ hist_g,
                                                 int E, int NBK, int NW) {
    __shared__ int lh[MAXBK];
    int t = threadIdx.x, w = blockIdx.x;
    for (int b = t; b < NBK; b += 256) lh[b] = 0;
    __syncthreads();
    int e0 = w * CHUNK;
#pragma unroll 4
    for (int i = 0; i < CHUNK / 256; i++) {
        int e = e0 + i * 256 + t;
        if (e < E) atomicAdd(&lh[edst[e] >> 5], 1);
    }
    __syncthreads();
    for (int b = t; b < NBK; b += 256) hist_g[(size_t)b * NW + w] = lh[b];
}

// Pass 2a: bucket totals.
__global__ __launch_bounds__(256) void s1_btot(const int* __restrict__ hist_g,
                                               int* __restrict__ btot,
                                               int NBK, int NW) {
    int b = blockIdx.x * 256 + threadIdx.x;
    if (b >= NBK) return;
    const int* row = &hist_g[(size_t)b * NW];
    int s = 0;
    for (int w = 0; w < NW; w++) s += row[w];
    btot[b] = s;
}

// Pass 2b: exclusive scan of bucket totals -> bbase[0..NBK], bbase[NBK]=E.
__global__ __launch_bounds__(256) void s2_scan(const int* __restrict__ btot,
                                               int* __restrict__ bbase, int NBK) {
    __shared__ int ls[MAXBK];
    __shared__ int ss[257];
    int t = threadIdx.x;
    const int CH = (MAXBK + 255) / 256;  // 13
    for (int b = t; b < NBK; b += 256) ls[b] = btot[b];
    __syncthreads();
    int s = 0;
    for (int i = 0; i < CH; i++) {
        int idx = t * CH + i;
        if (idx < NBK) s += ls[idx];
    }
    ss[t] = s;
    __syncthreads();
    if (t == 0) {
        int run = 0;
        for (int i = 0; i < 256; i++) { int v = ss[i]; ss[i] = run; run += v; }
        ss[256] = run;
    }
    __syncthreads();
    int run = ss[t];
    for (int i = 0; i < CH; i++) {
        int idx = t * CH + i;
        if (idx < NBK) { int v = ls[idx]; ls[idx] = run; run += v; }
    }
    __syncthreads();
    for (int b = t; b < NBK; b += 256) bbase[b] = ls[b];
    if (t == 0) bbase[NBK] = ss[256];
}

// Pass 2c: per-bucket row exclusive scan -> per-WG write bases.
__global__ __launch_bounds__(256) void s3_rowscan(int* __restrict__ hist_g,
                                                  const int* __restrict__ bbase,
                                                  int NBK, int NW) {
    int b = blockIdx.x * 256 + threadIdx.x;
    if (b >= NBK) return;
    int* row = &hist_g[(size_t)b * NW];
    int run = bbase[b];
    for (int w = 0; w < NW; w++) { int v = row[w]; row[w] = run; run += v; }
}

// Pass 3: scatter edges into WG-private per-bucket ranges (no global atomics).
__global__ __launch_bounds__(256) void scatter_pass(const int* __restrict__ esrc,
                                                    const int* __restrict__ edst,
                                                    const int* __restrict__ hist_g,
                                                    int* __restrict__ packed,
                                                    int E, int NBK, int NW) {
    __shared__ int cur[MAXBK];
    int t = threadIdx.x, w = blockIdx.x;
    for (int b = t; b < NBK; b += 256) cur[b] = hist_g[(size_t)b * NW + w];
    __syncthreads();
    int e0 = w * CHUNK;
#pragma unroll 4
    for (int i = 0; i < CHUNK / 256; i++) {
        int e = e0 + i * 256 + t;
        if (e < E) {
            int d = edst[e];
            int pos = atomicAdd(&cur[d >> 5], 1);
            packed[pos] = esrc[e] | ((d & 31) << 17);
        }
    }
}

// Pass 4: per-bucket counting sort by local dst -> dst-sorted CSR (packed2),
// per-node row pointers rp (inclusive end), and dinv. One WG per bucket.
__global__ __launch_bounds__(256) void bucket_sort(const int* __restrict__ packed,
                                                   const int* __restrict__ bbase,
                                                   int* __restrict__ packed2,
                                                   int* __restrict__ rp,
                                                   float* __restrict__ dinv, int M) {
    __shared__ int cnt[32];
    __shared__ int cur[32];
    int b = blockIdx.x, t = threadIdx.x;
    int start = bbase[b], end = bbase[b + 1];
    if (t < 32) cnt[t] = 0;
    __syncthreads();
    for (int e = start + t; e < end; e += 256)
        atomicAdd(&cnt[(packed[e] >> 17) & 31], 1);
    __syncthreads();
    if (t == 0) {
        int run = start;
        for (int i = 0; i < 32; i++) {
            cur[i] = run;
            run += cnt[i];
            int node = b * 32 + i;
            if (node < M) rp[node] = run;     // inclusive end of row
        }
    }
    if (t < 32) {
        int node = b * 32 + t;
        if (node < M) dinv[node] = rsqrtf((float)cnt[t] + 1.0f);  // +1 self loop
    }
    __syncthreads();
    for (int e = start + t; e < end; e += 256) {
        int p = packed[e];
        int pos = atomicAdd(&cur[(p >> 17) & 31], 1);
        packed2[pos] = p;
    }
}

// ========== weight prep: W1t[n][k]=bf16(W1[k][n]); W2t[n][k]=bf16(W2[k][n]) =====

__global__ __launch_bounds__(256) void cvt_W1t(const float* __restrict__ W1,
                                               unsigned short* __restrict__ W1t) {
    int n = blockIdx.x;  // 0..255
    for (int k = threadIdx.x; k < F_IN; k += 256)
        W1t[n * F_IN + k] = f2b(W1[(size_t)k * F_HID + n]);
}

__global__ __launch_bounds__(256) void cvt_W2t(const float* __restrict__ W2,
                                               unsigned short* __restrict__ W2t) {
    int n = blockIdx.x;   // 0..47 (padded)
    int k = threadIdx.x;  // 0..255
    W2t[n * F_HID + k] = (n < N_CLS) ? f2b(W2[(size_t)k * N_CLS + n])
                                     : (unsigned short)0;
}

// ====== MFMA GEMM1: h1s = dinv[m] * (bf16(x) @ bf16(W1))  (M x 512)@(512 x 256) ==
// 128x256 tile (full N in one block), BK=32, 512 threads = 8 waves (2x4 of 64x64).
// x read ONCE. Output pre-scaled by dinv[row], bf16.

__global__ __launch_bounds__(512) void mfma_gemm1(const float* __restrict__ A,
                                                  const unsigned short* __restrict__ Bt,
                                                  const float* __restrict__ dinv,
                                                  unsigned short* __restrict__ H1,
                                                  int M) {
    __shared__ unsigned short As[128 * 40];  // [m][k], row 40 shorts (pad)
    __shared__ unsigned short Bs[256 * 40];  // [n][k]
    int tid = threadIdx.x;
    int wave = tid >> 6, lane = tid & 63;
    int quad = lane >> 4, l15 = lane & 15;
    int m0 = blockIdx.x * 128;
    int wm = (wave & 1) * 64, wn = (wave >> 1) * 64;

    f32x4 acc[4][4] = {};

    int ar = tid >> 2, aq = tid & 3;   // A: row 0..127, 8-float quarter
    int bn = tid >> 1, bc = tid & 1;   // B: row(n) 0..255, chunk parity

    for (int k0 = 0; k0 < F_IN; k0 += 32) {
        // ---- stage A (f32 -> bf16) ----
        {
            int gm = m0 + ar;
            float4 v0, v1;
            if (gm < M) {
                const float4* ap = (const float4*)&A[(size_t)gm * F_IN + k0 + aq * 8];
                v0 = ap[0]; v1 = ap[1];
            } else {
                v0 = v1 = make_float4(0.f, 0.f, 0.f, 0.f);
            }
            u16x8 w;
            w[0]=f2b(v0.x); w[1]=f2b(v0.y); w[2]=f2b(v0.z); w[3]=f2b(v0.w);
            w[4]=f2b(v1.x); w[5]=f2b(v1.y); w[6]=f2b(v1.z); w[7]=f2b(v1.w);
            *(u16x8*)&As[ar * 40 + aq * 8] = w;
        }
        // ---- stage B (already bf16) ----
        {
            const unsigned short* bp = &Bt[(size_t)bn * F_IN + k0];
            *(u16x8*)&Bs[bn * 40 + bc * 8]       = *(const u16x8*)(bp + bc * 8);
            *(u16x8*)&Bs[bn * 40 + (bc + 2) * 8] = *(const u16x8*)(bp + bc * 8 + 16);
        }
        __syncthreads();
        bf16x8 af[4], bfr[4];
#pragma unroll
        for (int i = 0; i < 4; i++)
            af[i] = *(const bf16x8*)&As[(wm + i * 16 + l15) * 40 + quad * 8];
#pragma unroll
        for (int j = 0; j < 4; j++)
            bfr[j] = *(const bf16x8*)&Bs[(wn + j * 16 + l15) * 40 + quad * 8];
#pragma unroll
        for (int i = 0; i < 4; i++)
#pragma unroll
            for (int j = 0; j < 4; j++)
                acc[i][j] = __builtin_amdgcn_mfma_f32_16x16x32_bf16(
                    af[i], bfr[j], acc[i][j], 0, 0, 0);
        __syncthreads();
    }
    // ---- epilogue: C layout col=l15, row=quad*4+rr; pre-scale by dinv[row] ----
#pragma unroll
    for (int i = 0; i < 4; i++) {
#pragma unroll
        for (int rr = 0; rr < 4; rr++) {
            int gm = m0 + wm + i * 16 + quad * 4 + rr;
            if (gm < M) {
                float dv = dinv[gm];
#pragma unroll
                for (int j = 0; j < 4; j++) {
                    int gn = wn + j * 16 + l15;
                    H1[(size_t)gm * F_HID + gn] = f2b(dv * acc[i][j][rr]);
                }
            }
        }
    }
}

// ======= CSR aggregation layer 1 (F=256, bf16, dinv-prescaled) + bias + ReLU =====
// One wave per dst node; lane holds 4 bf16 feats; edge loop unrolled x8 for MLP.
// act1[r] = relu( dinv[r] * (sum_e h1s[col] + h1s[r]) + b1 )

__global__ __launch_bounds__(256) void csr_agg1(const int* __restrict__ rp,
                                                const int* __restrict__ col,
                                                const float* __restrict__ dinv,
                                                const unsigned short* __restrict__ h1,
                                                const float* __restrict__ b1,
                                                unsigned short* __restrict__ act1,
                                                int M) {
    int w = threadIdx.x >> 6, lane = threadIdx.x & 63;
    int r = blockIdx.x * 4 + w;
    if (r >= M) return;
    int start = r ? rp[r - 1] : 0;
    int end = rp[r];
    float dr = dinv[r];

    const ushort4* hv = (const ushort4*)h1;  // node stride 64 ushort4
    ushort4 v = hv[(size_t)r * 64 + lane];   // self term (already dinv[r]-scaled)
    float ax = b2f(v.x), ay = b2f(v.y), az = b2f(v.z), aw = b2f(v.w);

    int e = start;
    for (; e + 8 <= end; e += 8) {
        int s0 = col[e]     & PKMASK, s1 = col[e + 1] & PKMASK;
        int s2 = col[e + 2] & PKMASK, s3 = col[e + 3] & PKMASK;
        int s4 = col[e + 4] & PKMASK, s5 = col[e + 5] & PKMASK;
        int s6 = col[e + 6] & PKMASK, s7 = col[e + 7] & PKMASK;
        ushort4 q0 = hv[(size_t)s0 * 64 + lane];
        ushort4 q1 = hv[(size_t)s1 * 64 + lane];
        ushort4 q2 = hv[(size_t)s2 * 64 + lane];
        ushort4 q3 = hv[(size_t)s3 * 64 + lane];
        ushort4 q4 = hv[(size_t)s4 * 64 + lane];
        ushort4 q5 = hv[(size_t)s5 * 64 + lane];
        ushort4 q6 = hv[(size_t)s6 * 64 + lane];
        ushort4 q7 = hv[(size_t)s7 * 64 + lane];
        ax += ((b2f(q0.x) + b2f(q1.x)) + (b2f(q2.x) + b2f(q3.x)))
            + ((b2f(q4.x) + b2f(q5.x)) + (b2f(q6.x) + b2f(q7.x)));
        ay += ((b2f(q0.y) + b2f(q1.y)) + (b2f(q2.y) + b2f(q3.y)))
            + ((b2f(q4.y) + b2f(q5.y)) + (b2f(q6.y) + b2f(q7.y)));
        az += ((b2f(q0.z) + b2f(q1.z)) + (b2f(q2.z) + b2f(q3.z)))
            + ((b2f(q4.z) + b2f(q5.z)) + (b2f(q6.z) + b2f(q7.z)));
        aw += ((b2f(q0.w) + b2f(q1.w)) + (b2f(q2.w) + b2f(q3.w)))
            + ((b2f(q4.w) + b2f(q5.w)) + (b2f(q6.w) + b2f(q7.w)));
    }
    for (; e < end; e++) {
        ushort4 q = hv[(size_t)(col[e] & PKMASK) * 64 + lane];
        ax += b2f(q.x); ay += b2f(q.y); az += b2f(q.z); aw += b2f(q.w);
    }
    float4 bb = *(const float4*)&b1[lane * 4];
    ushort4 o;
    o.x = f2b(fmaxf(dr * ax + bb.x, 0.f));
    o.y = f2b(fmaxf(dr * ay + bb.y, 0.f));
    o.z = f2b(fmaxf(dr * az + bb.z, 0.f));
    o.w = f2b(fmaxf(dr * aw + bb.w, 0.f));
    ((ushort4*)act1)[(size_t)r * 64 + lane] = o;
}

// ===== MFMA GEMM2: h2s = dinv[m] * (act1 @ bf16(W2))  (M x 256)@(256 x 48pad) ===
// One wave per 16 rows; A frags straight from global (no LDS); W2t from L2.

__global__ __launch_bounds__(256) void mfma_gemm2(const unsigned short* __restrict__ act1,
                                                  const unsigned short* __restrict__ W2t,
                                                  const float* __restrict__ dinv,
                                                  float* __restrict__ h2, int M) {
    int wave = threadIdx.x >> 6, lane = threadIdx.x & 63;
    int quad = lane >> 4, l15 = lane & 15;
    int r0 = (blockIdx.x * 4 + wave) * 16;
    if (r0 >= M) return;

    f32x4 acc[3] = {};
    const unsigned short* arow = &act1[(size_t)(r0 + l15) * F_HID];
#pragma unroll
    for (int kt = 0; kt < F_HID; kt += 32) {
        bf16x8 af = *(const bf16x8*)&arow[kt + quad * 8];
#pragma unroll
        for (int j = 0; j < 3; j++) {
            bf16x8 bf = *(const bf16x8*)&W2t[(size_t)(j * 16 + l15) * F_HID + kt + quad * 8];
            acc[j] = __builtin_amdgcn_mfma_f32_16x16x32_bf16(af, bf, acc[j], 0, 0, 0);
        }
    }
    // C layout: col = l15 + j*16, row = quad*4 + rr; pre-scale by dinv[row]
#pragma unroll
    for (int j = 0; j < 3; j++) {
        int c = j * 16 + l15;
        if (c < N_CLS) {
#pragma unroll
            for (int rr = 0; rr < 4; rr++) {
                int r = r0 + quad * 4 + rr;
                h2[(size_t)r * N_CLS + c] = dinv[r] * acc[j][rr];
            }
        }
    }
}

// ===== CSR aggregation layer 2 (F=41, dinv-prescaled) + b2 + log_softmax ========

__global__ __launch_bounds__(256) void csr_agg2_lsm(const int* __restrict__ rp,
                                                    const int* __restrict__ col,
                                                    const float* __restrict__ dinv,
                                                    const float* __restrict__ h2,
                                                    const float* __restrict__ b2,
                                                    float* __restrict__ out, int M) {
    int w = threadIdx.x >> 6, lane = threadIdx.x & 63;
    int r = blockIdx.x * 4 + w;
    if (r >= M) return;
    int start = r ? rp[r - 1] : 0;
    int end = rp[r];
    float dr = dinv[r];

    float acc = 0.f;
    if (lane < N_CLS) acc = h2[(size_t)r * N_CLS + lane];  // self (prescaled)
    int e = start;
    for (; e + 4 <= end; e += 4) {
        int s0 = col[e] & PKMASK,     s1 = col[e + 1] & PKMASK;
        int s2 = col[e + 2] & PKMASK, s3 = col[e + 3] & PKMASK;
        if (lane < N_CLS) {
            float a0 = h2[(size_t)s0 * N_CLS + lane];
            float a1 = h2[(size_t)s1 * N_CLS + lane];
            float a2 = h2[(size_t)s2 * N_CLS + lane];
            float a3 = h2[(size_t)s3 * N_CLS + lane];
            acc += (a0 + a1) + (a2 + a3);
        }
    }
    for (; e < end; e++) {
        if (lane < N_CLS) acc += h2[(size_t)(col[e] & PKMASK) * N_CLS + lane];
    }
    float v = (lane < N_CLS) ? dr * acc + b2[lane] : -INFINITY;

    float m = v;
#pragma unroll
    for (int off = 32; off; off >>= 1) m = fmaxf(m, __shfl_xor(m, off));
    float ex = (lane < N_CLS) ? expf(v - m) : 0.f;
    float s = ex;
#pragma unroll
    for (int off = 32; off; off >>= 1) s += __shfl_xor(s, off);
    float ls = logf(s);
    if (lane < N_CLS) out[(size_t)r * N_CLS + lane] = v - m - ls;
}

// ================= launch =================

extern "C" void kernel_launch(void* const* d_in, const int* in_sizes, int n_in,
                              void* d_out, int out_size, void* d_ws, size_t ws_size,
                              hipStream_t stream) {
    const float* x  = (const float*)d_in[0];
    const int*   ei = (const int*)d_in[1];
    const float* W1 = (const float*)d_in[2];
    const float* b1 = (const float*)d_in[3];
    const float* W2 = (const float*)d_in[4];
    const float* b2 = (const float*)d_in[5];
    float* out = (float*)d_out;

    const int M = in_sizes[0] / F_IN;       // 100000
    const int E = in_sizes[1] / 2;          // 3200000
    const int* esrc = ei;
    const int* edst = ei + E;

    const int NBK = (M + 31) / 32;          // 3125 buckets of 32 dst nodes
    const int NW  = (E + CHUNK - 1) / CHUNK; // 196 edge chunks

    // workspace layout (bytes, 128-aligned)
    char* ws = (char*)d_ws;
    float*          dinv    = (float*)(ws);                         //     400,128
    int*            rp      = (int*)  (ws +    400128);             //     400,128
    int*            bbase   = (int*)  (ws +    800256);             //      12,544
    int*            btot    = (int*)  (ws +    812800);             //      12,544
    int*            hist_g  = (int*)  (ws +    825344);             //   2,450,048
    int*            packed  = (int*)  (ws +   3275392ull);          //  12,800,000
    int*            packed2 = (int*)  (ws +  16075392ull);          //  12,800,000
    unsigned short* W1t     = (unsigned short*)(ws + 28875392ull);  //     262,144
    unsigned short* W2t     = (unsigned short*)(ws + 29137536ull);  //      24,576
    unsigned short* h1      = (unsigned short*)(ws + 29162112ull);  //  51,200,000
    unsigned short* act1    = (unsigned short*)(ws + 80362112ull);  //  51,200,000
    float*          h2      = (float*)(ws + 131562112ull);          //  16,400,000

    // --- CSR build (bucketed, no global atomic storms) ---
    hist_pass<<<NW, 256, 0, stream>>>(edst, hist_g, E, NBK, NW);
    s1_btot<<<(NBK + 255) / 256, 256, 0, stream>>>(hist_g, btot, NBK, NW);
    s2_scan<<<1, 256, 0, stream>>>(btot, bbase, NBK);
    s3_rowscan<<<(NBK + 255) / 256, 256, 0, stream>>>(hist_g, bbase, NBK, NW);
    scatter_pass<<<NW, 256, 0, stream>>>(esrc, edst, hist_g, packed, E, NBK, NW);
    bucket_sort<<<NBK, 256, 0, stream>>>(packed, bbase, packed2, rp, dinv, M);

    // --- weight prep ---
    cvt_W1t<<<F_HID, 256, 0, stream>>>(W1, W1t);
    cvt_W2t<<<48, 256, 0, stream>>>(W2, W2t);

    // --- layer 1 ---
    mfma_gemm1<<<(M + 127) / 128, 512, 0, stream>>>(x, W1t, dinv, h1, M);
    csr_agg1<<<(M + 3) / 4, 256, 0, stream>>>(rp, packed2, dinv, h1, b1, act1, M);

    // --- layer 2 ---
    mfma_gemm2<<<(M / 16 + 3) / 4, 256, 0, stream>>>(act1, W2t, dinv, h2, M);
    csr_agg2_lsm<<<(M + 3) / 4, 256, 0, stream>>>(rp, packed2, dinv, h2, b2, out, M);
}